// Round 2
// baseline (420.579 us; speedup 1.0000x reference)
//
#include <hip/hip_runtime.h>

#define Bb 256
#define Nn 240
#define Ee 4338
#define Ff 28
#define Uu 100
#define Kk 128            // U + F
#define Mrows (Bb * Nn)   // 61440
#define ET (Ee + Nn)      // 4578 edges incl self-loops
#define XS 136            // LDS row stride (u16 elems): 272B = 68 dwords -> <=2-way bank alias
#define WCAP 2048         // cached edge weights per dst (deg max ~35 in practice)

typedef __attribute__((ext_vector_type(8))) short bf16x8;
typedef __attribute__((ext_vector_type(4))) float f32x4;
typedef unsigned short u16;

__device__ __forceinline__ float bf2f(u16 u) {
  union { unsigned int i; float f; } v; v.i = ((unsigned int)u) << 16; return v.f;
}
__device__ __forceinline__ u16 f2bf(float f) {
  union { float ff; unsigned int i; } v; v.ff = f;
  unsigned int x = v.i;
  return (u16)((x + 0x7fffu + ((x >> 16) & 1u)) >> 16);
}
__device__ __forceinline__ void splitbf(float v, u16& hi, u16& lo) {
  u16 h = f2bf(v);
  hi = h;
  lo = f2bf(v - bf2f(h));   // residual exact in fp32; lo rounds it (err ~2^-18 |v|)
}

// ---------------------------------------------------------------------------
// k_prep: fp32 weights -> padded/transposed bf16 hi/lo pairs.
// wg*: [112][128] (row=out col c, k contiguous); wru*: [208][128]; wc*: [112][128]
// ---------------------------------------------------------------------------
__global__ __launch_bounds__(256) void k_prep(
    const float* __restrict__ Wg, const float* __restrict__ Wru, const float* __restrict__ Wc,
    u16* __restrict__ wgh, u16* __restrict__ wgl,
    u16* __restrict__ wruh, u16* __restrict__ wrul,
    u16* __restrict__ wch, u16* __restrict__ wcl) {
  int gt = blockIdx.x * 256 + threadIdx.x, GS = gridDim.x * 256;
  for (int i = gt; i < 112 * Kk; i += GS) {
    int c = i >> 7, k = i & 127;
    float v = (c < Uu) ? Wg[c * Kk + k] : 0.f;
    splitbf(v, wgh[i], wgl[i]);
  }
  for (int i = gt; i < 208 * Kk; i += GS) {
    int n = i >> 7, k = i & 127;
    float v = (n < 2 * Uu) ? Wru[k * (2 * Uu) + n] : 0.f;
    splitbf(v, wruh[i], wrul[i]);
  }
  for (int i = gt; i < 112 * Kk; i += GS) {
    int n = i >> 7, k = i & 127;
    float v = (n < Uu) ? Wc[k * Uu + n] : 0.f;
    splitbf(v, wch[i], wcl[i]);
  }
}

// ---------------------------------------------------------------------------
// k_csr: dst-grouped CSR (+ self-loop per node), single block.
// ---------------------------------------------------------------------------
__global__ __launch_bounds__(256) void k_csr(
    const int* __restrict__ esrc, const int* __restrict__ edst,
    int* __restrict__ coff, int* __restrict__ cslot) {
  __shared__ int cnt[Nn];
  __shared__ int offs[Nn + 1];
  __shared__ int cur[Nn];
  int tid = threadIdx.x;
  for (int n = tid; n < Nn; n += 256) cnt[n] = 0;
  __syncthreads();
  for (int e = tid; e < Ee; e += 256) atomicAdd(&cnt[edst[e]], 1);
  __syncthreads();
  if (tid == 0) {
    int run = 0;
    for (int n = 0; n < Nn; ++n) { offs[n] = run; run += cnt[n] + 1; }
    offs[Nn] = run;
  }
  __syncthreads();
  for (int n = tid; n < Nn; n += 256) cur[n] = offs[n];
  for (int n = tid; n <= Nn; n += 256) coff[n] = offs[n];
  __syncthreads();
  for (int e = tid; e < Ee; e += 256) {
    int d = edst[e];
    int p = atomicAdd(&cur[d], 1);
    cslot[p] = esrc[e];
  }
  for (int n = tid; n < Nn; n += 256) {
    int p = atomicAdd(&cur[n], 1);
    cslot[p] = n;
  }
}

// ---------------------------------------------------------------------------
// k_gemm1: h[m,c] = sum_k x[m,k]*Wg[c,k], x=[state(100)|inputs(28)] fp32,
// via 3-term bf16 split MFMA (fp32-accurate). Also a_src[m], a_dst[m].
// ---------------------------------------------------------------------------
__global__ __launch_bounds__(256) void k_gemm1(
    const float* __restrict__ inp, const float* __restrict__ stt,
    const u16* __restrict__ wgh, const u16* __restrict__ wgl,
    const float* __restrict__ att_s, const float* __restrict__ att_d,
    float* __restrict__ h, float* __restrict__ asrc, float* __restrict__ adst) {
  __shared__ u16 xh[64 * XS];
  __shared__ u16 xl[64 * XS];
  int tid = threadIdx.x;
  int m0 = blockIdx.x * 64;
  for (int i = tid; i < 64 * Kk; i += 256) {
    int r = i >> 7, k = i & 127;
    int m = m0 + r, b = m / Nn, n = m - b * Nn;
    float v = (k < Uu) ? stt[b * (Nn * Uu) + n * Uu + k]
                       : inp[b * (Nn * Ff) + n * Ff + (k - Uu)];
    splitbf(v, xh[r * XS + k], xl[r * XS + k]);
  }
  __syncthreads();

  int w = tid >> 6, l = tid & 63;
  int l15 = l & 15, q = l >> 4;
  f32x4 acc[7];
  f32x4 zero = {0.f, 0.f, 0.f, 0.f};
#pragma unroll
  for (int t = 0; t < 7; ++t) acc[t] = zero;

  const u16* xrh = &xh[(w * 16 + l15) * XS + q * 8];
  const u16* xrl = &xl[(w * 16 + l15) * XS + q * 8];
#pragma unroll
  for (int s = 0; s < 4; ++s) {
    bf16x8 ah = *(const bf16x8*)(xrh + s * 32);
    bf16x8 al = *(const bf16x8*)(xrl + s * 32);
#pragma unroll
    for (int t = 0; t < 7; ++t) {
      const u16* wp = wgh + (t * 16 + l15) * Kk + s * 32 + q * 8;
      const u16* wq = wgl + (t * 16 + l15) * Kk + s * 32 + q * 8;
      bf16x8 bh = *(const bf16x8*)wp;
      bf16x8 bl = *(const bf16x8*)wq;
      acc[t] = __builtin_amdgcn_mfma_f32_16x16x32_bf16(ah, bh, acc[t], 0, 0, 0);
      acc[t] = __builtin_amdgcn_mfma_f32_16x16x32_bf16(al, bh, acc[t], 0, 0, 0);
      acc[t] = __builtin_amdgcn_mfma_f32_16x16x32_bf16(ah, bl, acc[t], 0, 0, 0);
    }
  }

  // C/D layout: col = l&15, row = q*4 + i  [m89]
  int mbase = m0 + w * 16;
  float sa[4] = {0.f, 0.f, 0.f, 0.f}, sd[4] = {0.f, 0.f, 0.f, 0.f};
#pragma unroll
  for (int t = 0; t < 7; ++t) {
    int c = t * 16 + l15;
    float av = (c < Uu) ? att_s[c] : 0.f;
    float dv = (c < Uu) ? att_d[c] : 0.f;
#pragma unroll
    for (int i = 0; i < 4; ++i) {
      float v = acc[t][i];
      if (c < Uu) h[(mbase + q * 4 + i) * Uu + c] = v;
      sa[i] += v * av;
      sd[i] += v * dv;
    }
  }
#pragma unroll
  for (int i = 0; i < 4; ++i) {
    float a_ = sa[i], d_ = sd[i];
#pragma unroll
    for (int msk = 1; msk < 16; msk <<= 1) {
      a_ += __shfl_xor(a_, msk, 64);
      d_ += __shfl_xor(d_, msk, 64);
    }
    if (l15 == i) {
      asrc[mbase + q * 4 + i] = a_;
      adst[mbase + q * 4 + i] = d_;
    }
  }
}

// ---------------------------------------------------------------------------
// k_attn: one block per (b,n). Weights w_e = exp(leaky(asrc[src]+adst[dst]))
// computed once into LDS; gstate = (sum w_e h[src]) / (sum w_e) + biases.
// (Identical math to max-subtracted softmax; scores bounded ~|3| here.)
// ---------------------------------------------------------------------------
__global__ __launch_bounds__(128) void k_attn(
    const int* __restrict__ coff, const int* __restrict__ cslot,
    const float* __restrict__ asrc, const float* __restrict__ adst,
    const float* __restrict__ h, const float* __restrict__ gbias, const float* __restrict__ b1,
    float* __restrict__ gsf) {
  __shared__ float wbuf[WCAP];
  __shared__ int sbuf[WCAP];
  int p = blockIdx.x;
  int b = p / Nn, n = p - b * Nn;
  int o0 = coff[n], deg = coff[n + 1] - o0;
  float ad = adst[p];
  int tid = threadIdx.x;

  for (int e = tid; e < deg; e += 128) {
    if (e < WCAP) {
      int s = cslot[o0 + e];
      float sc = asrc[b * Nn + s] + ad;
      sc = (sc > 0.f) ? sc : 0.2f * sc;
      wbuf[e] = __expf(sc);
      sbuf[e] = s;
    }
  }
  __syncthreads();

  float den = 0.f;
  for (int e = 0; e < deg; ++e) {
    float wv;
    if (e < WCAP) wv = wbuf[e];
    else {
      int s = cslot[o0 + e];
      float sc = asrc[b * Nn + s] + ad;
      sc = (sc > 0.f) ? sc : 0.2f * sc;
      wv = __expf(sc);
    }
    den += wv;
  }
  float inv = 1.f / den;

  int u = tid;
  if (u < Uu) {
    float acc = 0.f;
    for (int e = 0; e < deg; ++e) {
      int s; float wv;
      if (e < WCAP) { s = sbuf[e]; wv = wbuf[e]; }
      else {
        s = cslot[o0 + e];
        float sc = asrc[b * Nn + s] + ad;
        sc = (sc > 0.f) ? sc : 0.2f * sc;
        wv = __expf(sc);
      }
      acc += wv * h[(b * Nn + s) * Uu + u];
    }
    gsf[p * Uu + u] = acc * inv + gbias[u] + b1[u];
  }
}

// ---------------------------------------------------------------------------
// k_gru: cat=[xi|gstate] (split bf16 in LDS); ru=sigmoid(cat@Wru+bru);
// hidden2=r*st written back (split); c=tanh(cat2@Wc+bc); out=u*st+(1-u)*c.
// ---------------------------------------------------------------------------
__global__ __launch_bounds__(256) void k_gru(
    const float* __restrict__ inp, const float* __restrict__ gsf,
    const u16* __restrict__ wruh, const u16* __restrict__ wrul,
    const u16* __restrict__ wch, const u16* __restrict__ wcl,
    const float* __restrict__ bru, const float* __restrict__ bc,
    float* __restrict__ out) {
  __shared__ u16 ch[64 * XS];
  __shared__ u16 cl[64 * XS];
  __shared__ float ugL[64 * Uu];
  int tid = threadIdx.x;
  int m0 = blockIdx.x * 64;
  for (int i = tid; i < 64 * Kk; i += 256) {
    int r = i >> 7, k = i & 127;
    int m = m0 + r;
    float v;
    if (k < Ff) {
      int b = m / Nn, n = m - b * Nn;
      v = inp[b * (Nn * Ff) + n * Ff + k];
    } else {
      v = gsf[m * Uu + (k - Ff)];
    }
    splitbf(v, ch[r * XS + k], cl[r * XS + k]);
  }
  __syncthreads();

  int w = tid >> 6, l = tid & 63;
  int l15 = l & 15, q = l >> 4;
  int rbase = w * 16;
  const u16* arh = &ch[(rbase + l15) * XS + q * 8];
  const u16* arl = &cl[(rbase + l15) * XS + q * 8];
  f32x4 zero = {0.f, 0.f, 0.f, 0.f};

  // phase 1: ru (200 cols -> 13 tiles)
  f32x4 acc[13];
#pragma unroll
  for (int t = 0; t < 13; ++t) acc[t] = zero;
#pragma unroll
  for (int s = 0; s < 4; ++s) {
    bf16x8 ah = *(const bf16x8*)(arh + s * 32);
    bf16x8 al = *(const bf16x8*)(arl + s * 32);
#pragma unroll
    for (int t = 0; t < 13; ++t) {
      const u16* wp = wruh + (t * 16 + l15) * Kk + s * 32 + q * 8;
      const u16* wq = wrul + (t * 16 + l15) * Kk + s * 32 + q * 8;
      bf16x8 bh = *(const bf16x8*)wp;
      bf16x8 bl = *(const bf16x8*)wq;
      acc[t] = __builtin_amdgcn_mfma_f32_16x16x32_bf16(ah, bh, acc[t], 0, 0, 0);
      acc[t] = __builtin_amdgcn_mfma_f32_16x16x32_bf16(al, bh, acc[t], 0, 0, 0);
      acc[t] = __builtin_amdgcn_mfma_f32_16x16x32_bf16(ah, bl, acc[t], 0, 0, 0);
    }
  }
#pragma unroll
  for (int t = 0; t < 13; ++t) {
    int col = t * 16 + l15;
    if (col < 2 * Uu) {
      float bv = bru[col];
#pragma unroll
      for (int i = 0; i < 4; ++i) {
        int row = rbase + q * 4 + i;
        float g = 1.f / (1.f + __expf(-(acc[t][i] + bv)));
        if (col < Uu) {
          float stv = gsf[(m0 + row) * Uu + col];
          splitbf(g * stv, ch[row * XS + Ff + col], cl[row * XS + Ff + col]);
        } else {
          ugL[row * Uu + (col - Uu)] = g;
        }
      }
    }
  }
  __syncthreads();

  // phase 2: c (100 cols -> 7 tiles)
  f32x4 acc2[7];
#pragma unroll
  for (int t = 0; t < 7; ++t) acc2[t] = zero;
#pragma unroll
  for (int s = 0; s < 4; ++s) {
    bf16x8 ah = *(const bf16x8*)(arh + s * 32);
    bf16x8 al = *(const bf16x8*)(arl + s * 32);
#pragma unroll
    for (int t = 0; t < 7; ++t) {
      const u16* wp = wch + (t * 16 + l15) * Kk + s * 32 + q * 8;
      const u16* wq = wcl + (t * 16 + l15) * Kk + s * 32 + q * 8;
      bf16x8 bh = *(const bf16x8*)wp;
      bf16x8 bl = *(const bf16x8*)wq;
      acc2[t] = __builtin_amdgcn_mfma_f32_16x16x32_bf16(ah, bh, acc2[t], 0, 0, 0);
      acc2[t] = __builtin_amdgcn_mfma_f32_16x16x32_bf16(al, bh, acc2[t], 0, 0, 0);
      acc2[t] = __builtin_amdgcn_mfma_f32_16x16x32_bf16(ah, bl, acc2[t], 0, 0, 0);
    }
  }
#pragma unroll
  for (int t = 0; t < 7; ++t) {
    int col = t * 16 + l15;
    if (col < Uu) {
      float bv = bc[col];
#pragma unroll
      for (int i = 0; i < 4; ++i) {
        int row = rbase + q * 4 + i;
        float cv = tanhf(acc2[t][i] + bv);
        float ug = ugL[row * Uu + col];
        float sv = gsf[(m0 + row) * Uu + col];
        out[(m0 + row) * Uu + col] = ug * sv + (1.f - ug) * cv;
      }
    }
  }
}

// ---------------------------------------------------------------------------
extern "C" void kernel_launch(void* const* d_in, const int* in_sizes, int n_in,
                              void* d_out, int out_size, void* d_ws, size_t ws_size,
                              hipStream_t stream) {
  const float* inp   = (const float*)d_in[0];
  const float* stt   = (const float*)d_in[1];
  const int*   esrc  = (const int*)d_in[2];
  const int*   edst  = (const int*)d_in[3];
  const float* Wg    = (const float*)d_in[4];
  const float* att_s = (const float*)d_in[5];
  const float* att_d = (const float*)d_in[6];
  const float* gbias = (const float*)d_in[7];
  const float* b1    = (const float*)d_in[8];
  const float* Wru   = (const float*)d_in[9];
  const float* bru   = (const float*)d_in[10];
  const float* Wc    = (const float*)d_in[11];
  const float* bc    = (const float*)d_in[12];
  float* out = (float*)d_out;

  char* base = (char*)d_ws;
  size_t o = 0;
  auto alloc = [&](size_t bytes) -> void* {
    void* p = base + o;
    o = (o + bytes + 255) & ~(size_t)255;
    return p;
  };
  u16* wgh  = (u16*)alloc(112 * Kk * sizeof(u16));
  u16* wgl  = (u16*)alloc(112 * Kk * sizeof(u16));
  u16* wruh = (u16*)alloc(208 * Kk * sizeof(u16));
  u16* wrul = (u16*)alloc(208 * Kk * sizeof(u16));
  u16* wch  = (u16*)alloc(112 * Kk * sizeof(u16));
  u16* wcl  = (u16*)alloc(112 * Kk * sizeof(u16));
  int* coff  = (int*)alloc((Nn + 1) * sizeof(int));
  int* cslot = (int*)alloc(ET * sizeof(int));
  float* h    = (float*)alloc((size_t)Mrows * Uu * sizeof(float));
  float* asrc = (float*)alloc((size_t)Mrows * sizeof(float));
  float* adst = (float*)alloc((size_t)Mrows * sizeof(float));
  float* gsf  = (float*)alloc((size_t)Mrows * Uu * sizeof(float));

  k_prep<<<32, 256, 0, stream>>>(Wg, Wru, Wc, wgh, wgl, wruh, wrul, wch, wcl);
  k_csr<<<1, 256, 0, stream>>>(esrc, edst, coff, cslot);
  k_gemm1<<<Mrows / 64, 256, 0, stream>>>(inp, stt, wgh, wgl, att_s, att_d, h, asrc, adst);
  k_attn<<<Mrows, 128, 0, stream>>>(coff, cslot, asrc, adst, h, gbias, b1, gsf);
  k_gru<<<Mrows / 64, 256, 0, stream>>>(inp, gsf, wruh, wrul, wch, wcl, bru, bc, out);
}

// Round 3
// 324.001 us; speedup vs baseline: 1.2981x; 1.2981x over previous
//
#include <hip/hip_runtime.h>

#define Bb 256
#define Nn 240
#define Ee 4338
#define Ff 28
#define Uu 100
#define Kk 128            // U + F
#define Mrows (Bb * Nn)   // 61440
#define ET (Ee + Nn)      // edges incl self-loops
#define HTS 241           // hT leading stride (odd -> conflict-free)

typedef __attribute__((ext_vector_type(8))) short bf16x8;
typedef __attribute__((ext_vector_type(4))) float f32x4;
typedef unsigned short u16;

__device__ __forceinline__ float bf2f(u16 u) {
  union { unsigned int i; float f; } v; v.i = ((unsigned int)u) << 16; return v.f;
}
__device__ __forceinline__ u16 f2bf(float f) {
  union { float ff; unsigned int i; } v; v.ff = f;
  unsigned int x = v.i;
  return (u16)((x + 0x7fffu + ((x >> 16) & 1u)) >> 16);
}

// Build split-bf16 A-fragment from fp32 LDS cat row [xg(100) | xi(28)].
// k0 = s*32 + q*8; handles the single straddling range (96..103).
__device__ __forceinline__ void mkfrag(const float* xg, const float* xi, int row,
                                       int k0, bf16x8& hi, bf16x8& lo) {
  float v[8];
  if (k0 + 8 <= 100) {
    *(float4*)(v)     = *(const float4*)(xg + row * 100 + k0);
    *(float4*)(v + 4) = *(const float4*)(xg + row * 100 + k0 + 4);
  } else if (k0 >= 100) {
    *(float4*)(v)     = *(const float4*)(xi + row * 28 + (k0 - 100));
    *(float4*)(v + 4) = *(const float4*)(xi + row * 28 + (k0 - 96));
  } else {  // k0 == 96
    *(float4*)(v)     = *(const float4*)(xg + row * 100 + 96);
    *(float4*)(v + 4) = *(const float4*)(xi + row * 28);
  }
#pragma unroll
  for (int j = 0; j < 8; ++j) {
    u16 h = f2bf(v[j]);
    hi[j] = (short)h;
    lo[j] = (short)f2bf(v[j] - bf2f(h));
  }
}

// ---------------------------------------------------------------------------
// k_prep: fp32 weights -> padded/transposed bf16 hi/lo.
// wg: k-order [state(100)|inp(28)] (natural). wru/wc: k PERMUTED to
// [gstate(100)|xi(28)] (orig cat1 = [xi(28)|gstate(100)]).
// ---------------------------------------------------------------------------
__global__ __launch_bounds__(256) void k_prep(
    const float* __restrict__ Wg, const float* __restrict__ Wru, const float* __restrict__ Wc,
    u16* __restrict__ wgh, u16* __restrict__ wgl,
    u16* __restrict__ wruh, u16* __restrict__ wrul,
    u16* __restrict__ wch, u16* __restrict__ wcl) {
  int gt = blockIdx.x * 256 + threadIdx.x, GS = gridDim.x * 256;
  for (int i = gt; i < 112 * Kk; i += GS) {
    int c = i >> 7, k = i & 127;
    float v = (c < Uu) ? Wg[c * Kk + k] : 0.f;
    u16 h = f2bf(v); wgh[i] = h; wgl[i] = f2bf(v - bf2f(h));
  }
  for (int i = gt; i < 208 * Kk; i += GS) {
    int n = i >> 7, kp = i & 127;
    int k = (kp < Uu) ? (kp + Ff) : (kp - Uu);
    float v = (n < 2 * Uu) ? Wru[k * (2 * Uu) + n] : 0.f;
    u16 h = f2bf(v); wruh[i] = h; wrul[i] = f2bf(v - bf2f(h));
  }
  for (int i = gt; i < 112 * Kk; i += GS) {
    int n = i >> 7, kp = i & 127;
    int k = (kp < Uu) ? (kp + Ff) : (kp - Uu);
    float v = (n < Uu) ? Wc[k * Uu + n] : 0.f;
    u16 h = f2bf(v); wch[i] = h; wcl[i] = f2bf(v - bf2f(h));
  }
}

// ---------------------------------------------------------------------------
// k_csr: dst-grouped CSR (+ self-loop per node), single block.
// ---------------------------------------------------------------------------
__global__ __launch_bounds__(256) void k_csr(
    const int* __restrict__ esrc, const int* __restrict__ edst,
    int* __restrict__ coff, int* __restrict__ cslot) {
  __shared__ int cnt[Nn];
  __shared__ int offs[Nn + 1];
  __shared__ int cur[Nn];
  int tid = threadIdx.x;
  for (int n = tid; n < Nn; n += 256) cnt[n] = 0;
  __syncthreads();
  for (int e = tid; e < Ee; e += 256) atomicAdd(&cnt[edst[e]], 1);
  __syncthreads();
  if (tid == 0) {
    int run = 0;
    for (int n = 0; n < Nn; ++n) { offs[n] = run; run += cnt[n] + 1; }
    offs[Nn] = run;
  }
  __syncthreads();
  for (int n = tid; n < Nn; n += 256) cur[n] = offs[n];
  for (int n = tid; n <= Nn; n += 256) coff[n] = offs[n];
  __syncthreads();
  for (int e = tid; e < Ee; e += 256) {
    int d = edst[e];
    cslot[atomicAdd(&cur[d], 1)] = esrc[e];
  }
  for (int n = tid; n < Nn; n += 256) cslot[atomicAdd(&cur[n], 1)] = n;
}

// ---------------------------------------------------------------------------
// k_gemm1: h = x@Wg^T (x=[state|inp], fp32 in LDS, split-bf16 MFMA),
// plus a_src/a_dst row dots. 64 rows/block, 4 waves.
// ---------------------------------------------------------------------------
__global__ __launch_bounds__(256, 3) void k_gemm1(
    const float* __restrict__ inp, const float* __restrict__ stt,
    const u16* __restrict__ wgh, const u16* __restrict__ wgl,
    const float* __restrict__ att_s, const float* __restrict__ att_d,
    float* __restrict__ h, float* __restrict__ asrc, float* __restrict__ adst) {
  __shared__ __align__(16) float xg[64 * 100];
  __shared__ __align__(16) float xi[64 * 28];
  int tid = threadIdx.x;
  int m0 = blockIdx.x * 64;
  {  // flat float4 staging: both regions are contiguous in global memory
    const float4* gs = (const float4*)(stt + (size_t)m0 * Uu);
    const float4* gi = (const float4*)(inp + (size_t)m0 * Ff);
    float4* lg = (float4*)xg;
    float4* li = (float4*)xi;
    for (int j = tid; j < 1600; j += 256) lg[j] = gs[j];
    for (int j = tid; j < 448; j += 256) li[j] = gi[j];
  }
  __syncthreads();

  int w = tid >> 6, l = tid & 63;
  int l15 = l & 15, q = l >> 4;
  int row0 = w * 16;
  f32x4 acc[7];
  f32x4 zero = {0.f, 0.f, 0.f, 0.f};
#pragma unroll
  for (int t = 0; t < 7; ++t) acc[t] = zero;

#pragma unroll
  for (int s = 0; s < 4; ++s) {
    bf16x8 ah, al;
    mkfrag(xg, xi, row0 + l15, s * 32 + q * 8, ah, al);
#pragma unroll
    for (int t = 0; t < 7; ++t) {
      const u16* wp = wgh + (t * 16 + l15) * Kk + s * 32 + q * 8;
      const u16* wq = wgl + (t * 16 + l15) * Kk + s * 32 + q * 8;
      bf16x8 bh = *(const bf16x8*)wp;
      bf16x8 bl = *(const bf16x8*)wq;
      acc[t] = __builtin_amdgcn_mfma_f32_16x16x32_bf16(ah, bh, acc[t], 0, 0, 0);
      acc[t] = __builtin_amdgcn_mfma_f32_16x16x32_bf16(al, bh, acc[t], 0, 0, 0);
      acc[t] = __builtin_amdgcn_mfma_f32_16x16x32_bf16(ah, bl, acc[t], 0, 0, 0);
    }
  }

  // C/D layout: col = l&15, row = q*4 + i  [m89]
  int mbase = m0 + row0;
  float sa[4] = {0.f, 0.f, 0.f, 0.f}, sd[4] = {0.f, 0.f, 0.f, 0.f};
#pragma unroll
  for (int t = 0; t < 7; ++t) {
    int c = t * 16 + l15;
    float av = (c < Uu) ? att_s[c] : 0.f;
    float dv = (c < Uu) ? att_d[c] : 0.f;
#pragma unroll
    for (int i = 0; i < 4; ++i) {
      float v = acc[t][i];
      if (c < Uu) h[(size_t)(mbase + q * 4 + i) * Uu + c] = v;
      sa[i] += v * av;
      sd[i] += v * dv;
    }
  }
#pragma unroll
  for (int i = 0; i < 4; ++i) {
    float a_ = sa[i], d_ = sd[i];
#pragma unroll
    for (int msk = 1; msk < 16; msk <<= 1) {
      a_ += __shfl_xor(a_, msk, 64);
      d_ += __shfl_xor(d_, msk, 64);
    }
    if (l15 == i) {
      asrc[mbase + q * 4 + i] = a_;
      adst[mbase + q * 4 + i] = d_;
    }
  }
}

// ---------------------------------------------------------------------------
// k_attn: one block per SAMPLE. hT[100][241] fp32 in LDS (conflict-free),
// per-wave dst loop: lane-parallel edge weights, LDS-broadcast gather.
// ---------------------------------------------------------------------------
__global__ __launch_bounds__(512) void k_attn(
    const int* __restrict__ coff, const int* __restrict__ cslot,
    const float* __restrict__ asrc, const float* __restrict__ adst,
    const float* __restrict__ h, const float* __restrict__ gbias, const float* __restrict__ b1,
    float* __restrict__ gsf) {
  __shared__ float hT[Uu * HTS];
  __shared__ float asrcL[Nn];
  __shared__ float adstL[Nn];
  __shared__ float gbL[Uu];
  __shared__ float wtmp[8][64];
  __shared__ int stmp[8][64];
  int b = blockIdx.x;
  int tid = threadIdx.x;
  size_t base = (size_t)b * Nn * Uu;
  for (int i = tid; i < Nn; i += 512) {
    asrcL[i] = asrc[b * Nn + i];
    adstL[i] = adst[b * Nn + i];
  }
  for (int i = tid; i < Uu; i += 512) gbL[i] = gbias[i] + b1[i];
  for (int idx = tid; idx < Nn * Uu; idx += 512) {
    int n = idx / Uu, u = idx - n * Uu;
    hT[u * HTS + n] = h[base + idx];
  }
  __syncthreads();

  int wv = tid >> 6, lane = tid & 63;
  for (int n = wv; n < Nn; n += 8) {
    int o0 = coff[n], deg = coff[n + 1] - o0;
    float ad = adstL[n];
    float acc0 = 0.f, acc1 = 0.f, den = 0.f;
    for (int c0 = 0; c0 < deg; c0 += 64) {
      int e = c0 + lane;
      float we = 0.f; int s = 0;
      if (e < deg) {
        s = cslot[o0 + e];
        float sc = asrcL[s] + ad;
        sc = (sc > 0.f) ? sc : 0.2f * sc;
        we = __expf(sc);
      }
      wtmp[wv][lane] = we;
      stmp[wv][lane] = s;
      float d = we;
#pragma unroll
      for (int msk = 1; msk < 64; msk <<= 1) d += __shfl_xor(d, msk, 64);
      den += d;
      int cn = (deg - c0 < 64) ? (deg - c0) : 64;
      for (int e2 = 0; e2 < cn; ++e2) {
        float w_ = wtmp[wv][e2];     // same addr all lanes -> broadcast
        int s2 = stmp[wv][e2];
        acc0 += w_ * hT[lane * HTS + s2];
        if (lane < Uu - 64) acc1 += w_ * hT[(64 + lane) * HTS + s2];
      }
    }
    float inv = 1.f / den;
    size_t mb = base + (size_t)n * Uu;
    gsf[mb + lane] = acc0 * inv + gbL[lane];
    if (lane < Uu - 64) gsf[mb + 64 + lane] = acc1 * inv + gbL[64 + lane];
  }
}

// ---------------------------------------------------------------------------
// k_gru: cat=[gstate(100)|xi(28)] fp32 in LDS. Phase1 ru GEMM -> sigmoid;
// r*st written back into LDS gstate region (st from LDS); u-gate obtained
// in phase2 via in-wave shuffle from ru tiles 6..12. No mid-kernel barrier.
// ---------------------------------------------------------------------------
__global__ __launch_bounds__(256, 3) void k_gru(
    const float* __restrict__ inp, const float* __restrict__ gsf,
    const u16* __restrict__ wruh, const u16* __restrict__ wrul,
    const u16* __restrict__ wch, const u16* __restrict__ wcl,
    const float* __restrict__ bru, const float* __restrict__ bc,
    float* __restrict__ out) {
  __shared__ __align__(16) float xg[64 * 100];
  __shared__ __align__(16) float xi[64 * 28];
  int tid = threadIdx.x;
  int m0 = blockIdx.x * 64;
  {
    const float4* gs = (const float4*)(gsf + (size_t)m0 * Uu);
    const float4* gi = (const float4*)(inp + (size_t)m0 * Ff);
    float4* lg = (float4*)xg;
    float4* li = (float4*)xi;
    for (int j = tid; j < 1600; j += 256) lg[j] = gs[j];
    for (int j = tid; j < 448; j += 256) li[j] = gi[j];
  }
  __syncthreads();

  int w = tid >> 6, l = tid & 63;
  int l15 = l & 15, q = l >> 4;
  int row0 = w * 16;
  f32x4 zero = {0.f, 0.f, 0.f, 0.f};

  // phase 1: ru (200 cols -> 13 tiles)
  f32x4 acc[13];
#pragma unroll
  for (int t = 0; t < 13; ++t) acc[t] = zero;
#pragma unroll
  for (int s = 0; s < 4; ++s) {
    bf16x8 ah, al;
    mkfrag(xg, xi, row0 + l15, s * 32 + q * 8, ah, al);
#pragma unroll
    for (int t = 0; t < 13; ++t) {
      const u16* wp = wruh + (t * 16 + l15) * Kk + s * 32 + q * 8;
      const u16* wq = wrul + (t * 16 + l15) * Kk + s * 32 + q * 8;
      bf16x8 bh = *(const bf16x8*)wp;
      bf16x8 bl = *(const bf16x8*)wq;
      acc[t] = __builtin_amdgcn_mfma_f32_16x16x32_bf16(ah, bh, acc[t], 0, 0, 0);
      acc[t] = __builtin_amdgcn_mfma_f32_16x16x32_bf16(al, bh, acc[t], 0, 0, 0);
      acc[t] = __builtin_amdgcn_mfma_f32_16x16x32_bf16(ah, bl, acc[t], 0, 0, 0);
    }
  }

  // sigmoid everywhere; r (cols<100): write r*st into LDS gstate region.
  float sg[13][4];
#pragma unroll
  for (int t = 0; t < 13; ++t) {
    int col = t * 16 + l15;
    float bv = (col < 2 * Uu) ? bru[col] : 0.f;
#pragma unroll
    for (int i = 0; i < 4; ++i) {
      float g = 1.f / (1.f + __expf(-(acc[t][i] + bv)));
      sg[t][i] = g;
      if (col < Uu) {
        int row = row0 + q * 4 + i;
        float stv = xg[row * 100 + col];
        xg[row * 100 + col] = g * stv;   // same-wave rows only; in-order
      }
    }
  }

  // u-gate for phase2 (row,col c): ru col 100+c = tile 6+t2 (l15<12) or 7+t2,
  // source lane (l15+4)&15 within the same 16-group.
  float ug[7][4];
  int srcLane = q * 16 + ((l15 + 4) & 15);
#pragma unroll
  for (int t2 = 0; t2 < 7; ++t2) {
#pragma unroll
    for (int i = 0; i < 4; ++i) {
      float a6 = __shfl(sg[6 + t2][i], srcLane, 64);
      float a7 = (t2 < 6) ? __shfl(sg[7 + t2][i], srcLane, 64) : 0.f;
      ug[t2][i] = (l15 < 12) ? a6 : a7;
    }
  }

  // phase 2: c-GEMM (cat2 = [r*st | xi] already in LDS)
  f32x4 acc2[7];
#pragma unroll
  for (int t = 0; t < 7; ++t) acc2[t] = zero;
#pragma unroll
  for (int s = 0; s < 4; ++s) {
    bf16x8 ah, al;
    mkfrag(xg, xi, row0 + l15, s * 32 + q * 8, ah, al);
#pragma unroll
    for (int t = 0; t < 7; ++t) {
      const u16* wp = wch + (t * 16 + l15) * Kk + s * 32 + q * 8;
      const u16* wq = wcl + (t * 16 + l15) * Kk + s * 32 + q * 8;
      bf16x8 bh = *(const bf16x8*)wp;
      bf16x8 bl = *(const bf16x8*)wq;
      acc2[t] = __builtin_amdgcn_mfma_f32_16x16x32_bf16(ah, bh, acc2[t], 0, 0, 0);
      acc2[t] = __builtin_amdgcn_mfma_f32_16x16x32_bf16(al, bh, acc2[t], 0, 0, 0);
      acc2[t] = __builtin_amdgcn_mfma_f32_16x16x32_bf16(ah, bl, acc2[t], 0, 0, 0);
    }
  }
#pragma unroll
  for (int t = 0; t < 7; ++t) {
    int col = t * 16 + l15;
    if (col < Uu) {
      float bv = bc[col];
#pragma unroll
      for (int i = 0; i < 4; ++i) {
        int row = row0 + q * 4 + i;
        // fast tanh: 1 - 2/(e^{2y}+1)
        float y = acc2[t][i] + bv;
        float cv = 1.f - 2.f / (__expf(2.f * y) + 1.f);
        float g = ug[t][i];
        float sv = gsf[(size_t)(m0 + row) * Uu + col];  // original gstate
        out[(size_t)(m0 + row) * Uu + col] = g * sv + (1.f - g) * cv;
      }
    }
  }
}

// ---------------------------------------------------------------------------
extern "C" void kernel_launch(void* const* d_in, const int* in_sizes, int n_in,
                              void* d_out, int out_size, void* d_ws, size_t ws_size,
                              hipStream_t stream) {
  const float* inp   = (const float*)d_in[0];
  const float* stt   = (const float*)d_in[1];
  const int*   esrc  = (const int*)d_in[2];
  const int*   edst  = (const int*)d_in[3];
  const float* Wg    = (const float*)d_in[4];
  const float* att_s = (const float*)d_in[5];
  const float* att_d = (const float*)d_in[6];
  const float* gbias = (const float*)d_in[7];
  const float* b1    = (const float*)d_in[8];
  const float* Wru   = (const float*)d_in[9];
  const float* bru   = (const float*)d_in[10];
  const float* Wc    = (const float*)d_in[11];
  const float* bc    = (const float*)d_in[12];
  float* out = (float*)d_out;

  char* base = (char*)d_ws;
  size_t o = 0;
  auto alloc = [&](size_t bytes) -> void* {
    void* p = base + o;
    o = (o + bytes + 255) & ~(size_t)255;
    return p;
  };
  u16* wgh  = (u16*)alloc(112 * Kk * sizeof(u16));
  u16* wgl  = (u16*)alloc(112 * Kk * sizeof(u16));
  u16* wruh = (u16*)alloc(208 * Kk * sizeof(u16));
  u16* wrul = (u16*)alloc(208 * Kk * sizeof(u16));
  u16* wch  = (u16*)alloc(112 * Kk * sizeof(u16));
  u16* wcl  = (u16*)alloc(112 * Kk * sizeof(u16));
  int* coff  = (int*)alloc((Nn + 1) * sizeof(int));
  int* cslot = (int*)alloc(ET * sizeof(int));
  float* h    = (float*)alloc((size_t)Mrows * Uu * sizeof(float));
  float* asrc = (float*)alloc((size_t)Mrows * sizeof(float));
  float* adst = (float*)alloc((size_t)Mrows * sizeof(float));
  float* gsf  = (float*)alloc((size_t)Mrows * Uu * sizeof(float));

  k_prep<<<32, 256, 0, stream>>>(Wg, Wru, Wc, wgh, wgl, wruh, wrul, wch, wcl);
  k_csr<<<1, 256, 0, stream>>>(esrc, edst, coff, cslot);
  k_gemm1<<<Mrows / 64, 256, 0, stream>>>(inp, stt, wgh, wgl, att_s, att_d, h, asrc, adst);
  k_attn<<<Bb, 512, 0, stream>>>(coff, cslot, asrc, adst, h, gbias, b1, gsf);
  k_gru<<<Mrows / 64, 256, 0, stream>>>(inp, gsf, wruh, wrul, wch, wcl, bru, bc, out);
}

// Round 4
// 275.096 us; speedup vs baseline: 1.5288x; 1.1778x over previous
//
#include <hip/hip_runtime.h>

#define Bb 256
#define Nn 240
#define Ee 4338
#define Ff 28
#define Uu 100
#define Kk 128            // U + F
#define Mrows (Bb * Nn)   // 61440
#define ET (Ee + Nn)      // edges incl self-loops

typedef __attribute__((ext_vector_type(8))) short bf16x8;
typedef __attribute__((ext_vector_type(4))) float f32x4;
typedef unsigned short u16;

__device__ __forceinline__ float bf2f(u16 u) {
  union { unsigned int i; float f; } v; v.i = ((unsigned int)u) << 16; return v.f;
}
__device__ __forceinline__ u16 f2bf(float f) {
  union { float ff; unsigned int i; } v; v.ff = f;
  unsigned int x = v.i;
  return (u16)((x + 0x7fffu + ((x >> 16) & 1u)) >> 16);
}

// Build split-bf16 A-fragment from fp32 LDS cat row [xg(100) | xi(28)].
__device__ __forceinline__ void mkfrag(const float* xg, const float* xi, int row,
                                       int k0, bf16x8& hi, bf16x8& lo) {
  float v[8];
  if (k0 + 8 <= 100) {
    *(float4*)(v)     = *(const float4*)(xg + row * 100 + k0);
    *(float4*)(v + 4) = *(const float4*)(xg + row * 100 + k0 + 4);
  } else if (k0 >= 100) {
    *(float4*)(v)     = *(const float4*)(xi + row * 28 + (k0 - 100));
    *(float4*)(v + 4) = *(const float4*)(xi + row * 28 + (k0 - 96));
  } else {  // k0 == 96
    *(float4*)(v)     = *(const float4*)(xg + row * 100 + 96);
    *(float4*)(v + 4) = *(const float4*)(xi + row * 28);
  }
#pragma unroll
  for (int j = 0; j < 8; ++j) {
    u16 h = f2bf(v[j]);
    hi[j] = (short)h;
    lo[j] = (short)f2bf(v[j] - bf2f(h));
  }
}

// ---------------------------------------------------------------------------
// k_prep: fp32 weights -> padded/transposed bf16 hi/lo.
// ---------------------------------------------------------------------------
__global__ __launch_bounds__(256) void k_prep(
    const float* __restrict__ Wg, const float* __restrict__ Wru, const float* __restrict__ Wc,
    u16* __restrict__ wgh, u16* __restrict__ wgl,
    u16* __restrict__ wruh, u16* __restrict__ wrul,
    u16* __restrict__ wch, u16* __restrict__ wcl) {
  int gt = blockIdx.x * 256 + threadIdx.x, GS = gridDim.x * 256;
  for (int i = gt; i < 112 * Kk; i += GS) {
    int c = i >> 7, k = i & 127;
    float v = (c < Uu) ? Wg[c * Kk + k] : 0.f;
    u16 h = f2bf(v); wgh[i] = h; wgl[i] = f2bf(v - bf2f(h));
  }
  for (int i = gt; i < 208 * Kk; i += GS) {
    int n = i >> 7, kp = i & 127;
    int k = (kp < Uu) ? (kp + Ff) : (kp - Uu);
    float v = (n < 2 * Uu) ? Wru[k * (2 * Uu) + n] : 0.f;
    u16 h = f2bf(v); wruh[i] = h; wrul[i] = f2bf(v - bf2f(h));
  }
  for (int i = gt; i < 112 * Kk; i += GS) {
    int n = i >> 7, kp = i & 127;
    int k = (kp < Uu) ? (kp + Ff) : (kp - Uu);
    float v = (n < Uu) ? Wc[k * Uu + n] : 0.f;
    u16 h = f2bf(v); wch[i] = h; wcl[i] = f2bf(v - bf2f(h));
  }
}

// ---------------------------------------------------------------------------
// k_csr: dst-grouped CSR (+ self-loop per node), single block.
// ---------------------------------------------------------------------------
__global__ __launch_bounds__(256) void k_csr(
    const int* __restrict__ esrc, const int* __restrict__ edst,
    int* __restrict__ coff, int* __restrict__ cslot) {
  __shared__ int cnt[Nn];
  __shared__ int offs[Nn + 1];
  __shared__ int cur[Nn];
  int tid = threadIdx.x;
  for (int n = tid; n < Nn; n += 256) cnt[n] = 0;
  __syncthreads();
  for (int e = tid; e < Ee; e += 256) atomicAdd(&cnt[edst[e]], 1);
  __syncthreads();
  if (tid == 0) {
    int run = 0;
    for (int n = 0; n < Nn; ++n) { offs[n] = run; run += cnt[n] + 1; }
    offs[Nn] = run;
  }
  __syncthreads();
  for (int n = tid; n < Nn; n += 256) cur[n] = offs[n];
  for (int n = tid; n <= Nn; n += 256) coff[n] = offs[n];
  __syncthreads();
  for (int e = tid; e < Ee; e += 256) {
    int d = edst[e];
    cslot[atomicAdd(&cur[d], 1)] = esrc[e];
  }
  for (int n = tid; n < Nn; n += 256) cslot[atomicAdd(&cur[n], 1)] = n;
}

// ---------------------------------------------------------------------------
// k_gemm1: h = x@Wg^T (x=[state|inp], fp32 in LDS, split-bf16 MFMA),
// plus a_src/a_dst row dots.
// ---------------------------------------------------------------------------
__global__ __launch_bounds__(256, 3) void k_gemm1(
    const float* __restrict__ inp, const float* __restrict__ stt,
    const u16* __restrict__ wgh, const u16* __restrict__ wgl,
    const float* __restrict__ att_s, const float* __restrict__ att_d,
    float* __restrict__ h, float* __restrict__ asrc, float* __restrict__ adst) {
  __shared__ __align__(16) float xg[64 * 100];
  __shared__ __align__(16) float xi[64 * 28];
  int tid = threadIdx.x;
  int m0 = blockIdx.x * 64;
  {
    const float4* gs = (const float4*)(stt + (size_t)m0 * Uu);
    const float4* gi = (const float4*)(inp + (size_t)m0 * Ff);
    float4* lg = (float4*)xg;
    float4* li = (float4*)xi;
    for (int j = tid; j < 1600; j += 256) lg[j] = gs[j];
    for (int j = tid; j < 448; j += 256) li[j] = gi[j];
  }
  __syncthreads();

  int w = tid >> 6, l = tid & 63;
  int l15 = l & 15, q = l >> 4;
  int row0 = w * 16;
  f32x4 acc[7];
  f32x4 zero = {0.f, 0.f, 0.f, 0.f};
#pragma unroll
  for (int t = 0; t < 7; ++t) acc[t] = zero;

#pragma unroll
  for (int s = 0; s < 4; ++s) {
    bf16x8 ah, al;
    mkfrag(xg, xi, row0 + l15, s * 32 + q * 8, ah, al);
#pragma unroll
    for (int t = 0; t < 7; ++t) {
      const u16* wp = wgh + (t * 16 + l15) * Kk + s * 32 + q * 8;
      const u16* wq = wgl + (t * 16 + l15) * Kk + s * 32 + q * 8;
      bf16x8 bh = *(const bf16x8*)wp;
      bf16x8 bl = *(const bf16x8*)wq;
      acc[t] = __builtin_amdgcn_mfma_f32_16x16x32_bf16(ah, bh, acc[t], 0, 0, 0);
      acc[t] = __builtin_amdgcn_mfma_f32_16x16x32_bf16(al, bh, acc[t], 0, 0, 0);
      acc[t] = __builtin_amdgcn_mfma_f32_16x16x32_bf16(ah, bl, acc[t], 0, 0, 0);
    }
  }

  int mbase = m0 + row0;
  float sa[4] = {0.f, 0.f, 0.f, 0.f}, sd[4] = {0.f, 0.f, 0.f, 0.f};
#pragma unroll
  for (int t = 0; t < 7; ++t) {
    int c = t * 16 + l15;
    float av = (c < Uu) ? att_s[c] : 0.f;
    float dv = (c < Uu) ? att_d[c] : 0.f;
#pragma unroll
    for (int i = 0; i < 4; ++i) {
      float v = acc[t][i];
      if (c < Uu) h[(size_t)(mbase + q * 4 + i) * Uu + c] = v;
      sa[i] += v * av;
      sd[i] += v * dv;
    }
  }
#pragma unroll
  for (int i = 0; i < 4; ++i) {
    float a_ = sa[i], d_ = sd[i];
#pragma unroll
    for (int msk = 1; msk < 16; msk <<= 1) {
      a_ += __shfl_xor(a_, msk, 64);
      d_ += __shfl_xor(d_, msk, 64);
    }
    if (l15 == i) {
      asrc[mbase + q * 4 + i] = a_;
      adst[mbase + q * 4 + i] = d_;
    }
  }
}

// ---------------------------------------------------------------------------
// k_attn: one WAVE per (sample b, dst n). No LDS. Lanes compute edge weights
// in parallel (+shuffle-reduce denom); gather reads h rows straight from
// L2 as float4, 2 edges/iter (one per half-wave), weights via shuffle.
// Grid (256, 60): blockIdx.x = sample -> same-sample blocks share an XCD
// under the typical id%8 mapping (perf heuristic only).
// ---------------------------------------------------------------------------
__global__ __launch_bounds__(256) void k_attn(
    const int* __restrict__ coff, const int* __restrict__ cslot,
    const float* __restrict__ asrc, const float* __restrict__ adst,
    const float* __restrict__ h, const float* __restrict__ gbias, const float* __restrict__ b1,
    float* __restrict__ gsf) {
  int b = blockIdx.x;
  int w = threadIdx.x >> 6, lane = threadIdx.x & 63;
  int n = blockIdx.y * 4 + w;
  int o0 = coff[n], deg = coff[n + 1] - o0;
  float ad = adst[b * Nn + n];
  const float* hb = h + (size_t)b * Nn * Uu;
  int half = lane >> 5, ll = lane & 31;
  bool act = (ll < 25);

  float ax = 0.f, ay = 0.f, az = 0.f, aw = 0.f;
  float den = 0.f;
  for (int c0 = 0; c0 < deg; c0 += 64) {
    int e = c0 + lane;
    float we = 0.f; int s = 0;
    if (e < deg) {
      s = cslot[o0 + e];
      float sc = asrc[b * Nn + s] + ad;
      sc = (sc > 0.f) ? sc : 0.2f * sc;
      we = __expf(sc);
    }
    float d = we;
#pragma unroll
    for (int msk = 1; msk < 64; msk <<= 1) d += __shfl_xor(d, msk, 64);
    den += d;

    int cn = (deg - c0 < 64) ? (deg - c0) : 64;
    for (int e2 = 0; e2 < cn; e2 += 2) {
      int eh = e2 + half;                       // eh <= 63 always (cn<=64)
      float w2 = __shfl(we, eh, 64);            // 0 for eh >= cn (padded lanes)
      int s2 = __shfl(s, eh, 64);
      if (act && eh < cn) {
        const float4 hv = *(const float4*)(hb + (size_t)s2 * Uu + ll * 4);
        ax += w2 * hv.x; ay += w2 * hv.y; az += w2 * hv.z; aw += w2 * hv.w;
      }
    }
  }
  // combine the two half-wave accumulators
  ax += __shfl_xor(ax, 32, 64);
  ay += __shfl_xor(ay, 32, 64);
  az += __shfl_xor(az, 32, 64);
  aw += __shfl_xor(aw, 32, 64);
  if (lane < 25) {
    float inv = 1.f / den;
    int u0 = lane * 4;
    float4 o;
    o.x = ax * inv + gbias[u0 + 0] + b1[u0 + 0];
    o.y = ay * inv + gbias[u0 + 1] + b1[u0 + 1];
    o.z = az * inv + gbias[u0 + 2] + b1[u0 + 2];
    o.w = aw * inv + gbias[u0 + 3] + b1[u0 + 3];
    *(float4*)(gsf + ((size_t)b * Nn + n) * Uu + u0) = o;
  }
}

// ---------------------------------------------------------------------------
// k_gru: cat=[gstate(100)|xi(28)] fp32 in LDS. Phase1 ru GEMM -> sigmoid;
// r*st back into LDS; u-gate via in-wave shuffle; phase2 c-GEMM; blend.
// ---------------------------------------------------------------------------
__global__ __launch_bounds__(256, 3) void k_gru(
    const float* __restrict__ inp, const float* __restrict__ gsf,
    const u16* __restrict__ wruh, const u16* __restrict__ wrul,
    const u16* __restrict__ wch, const u16* __restrict__ wcl,
    const float* __restrict__ bru, const float* __restrict__ bc,
    float* __restrict__ out) {
  __shared__ __align__(16) float xg[64 * 100];
  __shared__ __align__(16) float xi[64 * 28];
  int tid = threadIdx.x;
  int m0 = blockIdx.x * 64;
  {
    const float4* gs = (const float4*)(gsf + (size_t)m0 * Uu);
    const float4* gi = (const float4*)(inp + (size_t)m0 * Ff);
    float4* lg = (float4*)xg;
    float4* li = (float4*)xi;
    for (int j = tid; j < 1600; j += 256) lg[j] = gs[j];
    for (int j = tid; j < 448; j += 256) li[j] = gi[j];
  }
  __syncthreads();

  int w = tid >> 6, l = tid & 63;
  int l15 = l & 15, q = l >> 4;
  int row0 = w * 16;
  f32x4 zero = {0.f, 0.f, 0.f, 0.f};

  f32x4 acc[13];
#pragma unroll
  for (int t = 0; t < 13; ++t) acc[t] = zero;
#pragma unroll
  for (int s = 0; s < 4; ++s) {
    bf16x8 ah, al;
    mkfrag(xg, xi, row0 + l15, s * 32 + q * 8, ah, al);
#pragma unroll
    for (int t = 0; t < 13; ++t) {
      const u16* wp = wruh + (t * 16 + l15) * Kk + s * 32 + q * 8;
      const u16* wq = wrul + (t * 16 + l15) * Kk + s * 32 + q * 8;
      bf16x8 bh = *(const bf16x8*)wp;
      bf16x8 bl = *(const bf16x8*)wq;
      acc[t] = __builtin_amdgcn_mfma_f32_16x16x32_bf16(ah, bh, acc[t], 0, 0, 0);
      acc[t] = __builtin_amdgcn_mfma_f32_16x16x32_bf16(al, bh, acc[t], 0, 0, 0);
      acc[t] = __builtin_amdgcn_mfma_f32_16x16x32_bf16(ah, bl, acc[t], 0, 0, 0);
    }
  }

  float sg[13][4];
#pragma unroll
  for (int t = 0; t < 13; ++t) {
    int col = t * 16 + l15;
    float bv = (col < 2 * Uu) ? bru[col] : 0.f;
#pragma unroll
    for (int i = 0; i < 4; ++i) {
      float g = 1.f / (1.f + __expf(-(acc[t][i] + bv)));
      sg[t][i] = g;
      if (col < Uu) {
        int row = row0 + q * 4 + i;
        float stv = xg[row * 100 + col];
        xg[row * 100 + col] = g * stv;
      }
    }
  }

  float ug[7][4];
  int srcLane = q * 16 + ((l15 + 4) & 15);
#pragma unroll
  for (int t2 = 0; t2 < 7; ++t2) {
#pragma unroll
    for (int i = 0; i < 4; ++i) {
      float a6 = __shfl(sg[6 + t2][i], srcLane, 64);
      float a7 = (t2 < 6) ? __shfl(sg[7 + t2][i], srcLane, 64) : 0.f;
      ug[t2][i] = (l15 < 12) ? a6 : a7;
    }
  }

  f32x4 acc2[7];
#pragma unroll
  for (int t = 0; t < 7; ++t) acc2[t] = zero;
#pragma unroll
  for (int s = 0; s < 4; ++s) {
    bf16x8 ah, al;
    mkfrag(xg, xi, row0 + l15, s * 32 + q * 8, ah, al);
#pragma unroll
    for (int t = 0; t < 7; ++t) {
      const u16* wp = wch + (t * 16 + l15) * Kk + s * 32 + q * 8;
      const u16* wq = wcl + (t * 16 + l15) * Kk + s * 32 + q * 8;
      bf16x8 bh = *(const bf16x8*)wp;
      bf16x8 bl = *(const bf16x8*)wq;
      acc2[t] = __builtin_amdgcn_mfma_f32_16x16x32_bf16(ah, bh, acc2[t], 0, 0, 0);
      acc2[t] = __builtin_amdgcn_mfma_f32_16x16x32_bf16(al, bh, acc2[t], 0, 0, 0);
      acc2[t] = __builtin_amdgcn_mfma_f32_16x16x32_bf16(ah, bl, acc2[t], 0, 0, 0);
    }
  }
#pragma unroll
  for (int t = 0; t < 7; ++t) {
    int col = t * 16 + l15;
    if (col < Uu) {
      float bv = bc[col];
#pragma unroll
      for (int i = 0; i < 4; ++i) {
        int row = row0 + q * 4 + i;
        float y = acc2[t][i] + bv;
        float cv = 1.f - 2.f / (__expf(2.f * y) + 1.f);
        float g = ug[t][i];
        float sv = gsf[(size_t)(m0 + row) * Uu + col];
        out[(size_t)(m0 + row) * Uu + col] = g * sv + (1.f - g) * cv;
      }
    }
  }
}

// ---------------------------------------------------------------------------
extern "C" void kernel_launch(void* const* d_in, const int* in_sizes, int n_in,
                              void* d_out, int out_size, void* d_ws, size_t ws_size,
                              hipStream_t stream) {
  const float* inp   = (const float*)d_in[0];
  const float* stt   = (const float*)d_in[1];
  const int*   esrc  = (const int*)d_in[2];
  const int*   edst  = (const int*)d_in[3];
  const float* Wg    = (const float*)d_in[4];
  const float* att_s = (const float*)d_in[5];
  const float* att_d = (const float*)d_in[6];
  const float* gbias = (const float*)d_in[7];
  const float* b1    = (const float*)d_in[8];
  const float* Wru   = (const float*)d_in[9];
  const float* bru   = (const float*)d_in[10];
  const float* Wc    = (const float*)d_in[11];
  const float* bc    = (const float*)d_in[12];
  float* out = (float*)d_out;

  char* base = (char*)d_ws;
  size_t o = 0;
  auto alloc = [&](size_t bytes) -> void* {
    void* p = base + o;
    o = (o + bytes + 255) & ~(size_t)255;
    return p;
  };
  u16* wgh  = (u16*)alloc(112 * Kk * sizeof(u16));
  u16* wgl  = (u16*)alloc(112 * Kk * sizeof(u16));
  u16* wruh = (u16*)alloc(208 * Kk * sizeof(u16));
  u16* wrul = (u16*)alloc(208 * Kk * sizeof(u16));
  u16* wch  = (u16*)alloc(112 * Kk * sizeof(u16));
  u16* wcl  = (u16*)alloc(112 * Kk * sizeof(u16));
  int* coff  = (int*)alloc((Nn + 1) * sizeof(int));
  int* cslot = (int*)alloc(ET * sizeof(int));
  float* h    = (float*)alloc((size_t)Mrows * Uu * sizeof(float));
  float* asrc = (float*)alloc((size_t)Mrows * sizeof(float));
  float* adst = (float*)alloc((size_t)Mrows * sizeof(float));
  float* gsf  = (float*)alloc((size_t)Mrows * Uu * sizeof(float));

  k_prep<<<32, 256, 0, stream>>>(Wg, Wru, Wc, wgh, wgl, wruh, wrul, wch, wcl);
  k_csr<<<1, 256, 0, stream>>>(esrc, edst, coff, cslot);
  k_gemm1<<<Mrows / 64, 256, 0, stream>>>(inp, stt, wgh, wgl, att_s, att_d, h, asrc, adst);
  k_attn<<<dim3(Bb, 60), 256, 0, stream>>>(coff, cslot, asrc, adst, h, gbias, b1, gsf);
  k_gru<<<Mrows / 64, 256, 0, stream>>>(inp, gsf, wruh, wrul, wch, wcl, bru, bc, out);
}

// Round 6
// 251.853 us; speedup vs baseline: 1.6699x; 1.0923x over previous
//
#include <hip/hip_runtime.h>

#define Bb 256
#define Nn 240
#define Ee 4338
#define Ff 28
#define Uu 100
#define Kk 128            // U + F
#define Mrows (Bb * Nn)   // 61440
#define ET (Ee + Nn)      // edges incl self-loops
#define AS 136            // LDS A-panel row stride in u16 (272B -> <=2-way bank alias)

typedef __attribute__((ext_vector_type(8))) short bf16x8;
typedef __attribute__((ext_vector_type(4))) float f32x4;
typedef unsigned short u16;

__device__ __forceinline__ float bf2f(u16 u) {
  union { unsigned int i; float f; } v; v.i = ((unsigned int)u) << 16; return v.f;
}
__device__ __forceinline__ u16 f2bf(float f) {
  union { float ff; unsigned int i; } v; v.ff = f;
  unsigned int x = v.i;
  return (u16)((x + 0x7fffu + ((x >> 16) & 1u)) >> 16);
}
__device__ __forceinline__ void split4(const float4 v, ushort4& h, ushort4& l) {
  u16 h0 = f2bf(v.x), h1 = f2bf(v.y), h2 = f2bf(v.z), h3 = f2bf(v.w);
  h.x = h0; h.y = h1; h.z = h2; h.w = h3;
  l.x = f2bf(v.x - bf2f(h0)); l.y = f2bf(v.y - bf2f(h1));
  l.z = f2bf(v.z - bf2f(h2)); l.w = f2bf(v.w - bf2f(h3));
}

// ---------------------------------------------------------------------------
// k_prep: fp32 weights -> padded/transposed bf16 hi/lo.
// wg: 8 tiles (128 rows, k natural [state|inp]). wru: 16 tiles (256 rows),
// wc: 8 tiles (128 rows); both with k permuted to [gstate(100)|xi(28)].
// ---------------------------------------------------------------------------
__global__ __launch_bounds__(256) void k_prep(
    const float* __restrict__ Wg, const float* __restrict__ Wru, const float* __restrict__ Wc,
    u16* __restrict__ wgh, u16* __restrict__ wgl,
    u16* __restrict__ wruh, u16* __restrict__ wrul,
    u16* __restrict__ wch, u16* __restrict__ wcl) {
  int gt = blockIdx.x * 256 + threadIdx.x, GS = gridDim.x * 256;
  for (int i = gt; i < 128 * Kk; i += GS) {
    int c = i >> 7, k = i & 127;
    float v = (c < Uu) ? Wg[c * Kk + k] : 0.f;
    u16 h = f2bf(v); wgh[i] = h; wgl[i] = f2bf(v - bf2f(h));
  }
  for (int i = gt; i < 256 * Kk; i += GS) {
    int n = i >> 7, kp = i & 127;
    int k = (kp < Uu) ? (kp + Ff) : (kp - Uu);
    float v = (n < 2 * Uu) ? Wru[k * (2 * Uu) + n] : 0.f;
    u16 h = f2bf(v); wruh[i] = h; wrul[i] = f2bf(v - bf2f(h));
  }
  for (int i = gt; i < 128 * Kk; i += GS) {
    int n = i >> 7, kp = i & 127;
    int k = (kp < Uu) ? (kp + Ff) : (kp - Uu);
    float v = (n < Uu) ? Wc[k * Uu + n] : 0.f;
    u16 h = f2bf(v); wch[i] = h; wcl[i] = f2bf(v - bf2f(h));
  }
}

// ---------------------------------------------------------------------------
// k_csr: dst-grouped CSR (+ self-loop per node), single block.
// ---------------------------------------------------------------------------
__global__ __launch_bounds__(256) void k_csr(
    const int* __restrict__ esrc, const int* __restrict__ edst,
    int* __restrict__ coff, int* __restrict__ cslot) {
  __shared__ int cnt[Nn];
  __shared__ int offs[Nn + 1];
  __shared__ int cur[Nn];
  int tid = threadIdx.x;
  for (int n = tid; n < Nn; n += 256) cnt[n] = 0;
  __syncthreads();
  for (int e = tid; e < Ee; e += 256) atomicAdd(&cnt[edst[e]], 1);
  __syncthreads();
  if (tid == 0) {
    int run = 0;
    for (int n = 0; n < Nn; ++n) { offs[n] = run; run += cnt[n] + 1; }
    offs[Nn] = run;
  }
  __syncthreads();
  for (int n = tid; n < Nn; n += 256) cur[n] = offs[n];
  for (int n = tid; n <= Nn; n += 256) coff[n] = offs[n];
  __syncthreads();
  for (int e = tid; e < Ee; e += 256) {
    int d = edst[e];
    cslot[atomicAdd(&cur[d], 1)] = esrc[e];
  }
  for (int n = tid; n < Nn; n += 256) cslot[atomicAdd(&cur[n], 1)] = n;
}

// ---------------------------------------------------------------------------
// k_gemm1 (weight-stationary): each wave owns col-tiles {w, w+4}, preloads
// weights to VGPRs; K-loop is ds_read+MFMA only. asrc/adst via LDS atomics.
// ---------------------------------------------------------------------------
__global__ __launch_bounds__(256, 3) void k_gemm1(
    const float* __restrict__ stt, const float* __restrict__ inp,
    const u16* __restrict__ wgh, const u16* __restrict__ wgl,
    const float* __restrict__ att_s, const float* __restrict__ att_d,
    float* __restrict__ h, float* __restrict__ asrc, float* __restrict__ adst) {
  __shared__ u16 ahL[64 * AS];
  __shared__ u16 alL[64 * AS];
  __shared__ float sredA[64], sredD[64];
  int tid = threadIdx.x;
  int m0 = blockIdx.x * 64;
  if (tid < 64) sredA[tid] = 0.f;
  else if (tid < 128) sredD[tid - 64] = 0.f;
  for (int j = tid; j < 64 * 32; j += 256) {
    int r = j >> 5, g = j & 31;
    float4 v = (g < 25) ? *(const float4*)(stt + (size_t)(m0 + r) * Uu + g * 4)
                        : *(const float4*)(inp + (size_t)(m0 + r) * Ff + (g - 25) * 4);
    ushort4 hh, ll;
    split4(v, hh, ll);
    *(ushort4*)(ahL + r * AS + g * 4) = hh;
    *(ushort4*)(alL + r * AS + g * 4) = ll;
  }
  __syncthreads();

  int w = tid >> 6, l = tid & 63, l15 = l & 15, q = l >> 4;
  int T0 = w, T1 = w + 4;
  bf16x8 w0h[4], w0l[4], w1h[4], w1l[4];
#pragma unroll
  for (int s = 0; s < 4; ++s) {
    const int o0 = (T0 * 16 + l15) * Kk + s * 32 + q * 8;
    const int o1 = (T1 * 16 + l15) * Kk + s * 32 + q * 8;
    w0h[s] = *(const bf16x8*)(wgh + o0);
    w0l[s] = *(const bf16x8*)(wgl + o0);
    w1h[s] = *(const bf16x8*)(wgh + o1);
    w1l[s] = *(const bf16x8*)(wgl + o1);
  }
  f32x4 zero = {0.f, 0.f, 0.f, 0.f};
  f32x4 acc0[4], acc1[4];
#pragma unroll
  for (int rt = 0; rt < 4; ++rt) { acc0[rt] = zero; acc1[rt] = zero; }
#pragma unroll
  for (int rt = 0; rt < 4; ++rt) {
#pragma unroll
    for (int s = 0; s < 4; ++s) {
      bf16x8 a = *(const bf16x8*)(ahL + (rt * 16 + l15) * AS + s * 32 + q * 8);
      bf16x8 b = *(const bf16x8*)(alL + (rt * 16 + l15) * AS + s * 32 + q * 8);
      acc0[rt] = __builtin_amdgcn_mfma_f32_16x16x32_bf16(a, w0h[s], acc0[rt], 0, 0, 0);
      acc1[rt] = __builtin_amdgcn_mfma_f32_16x16x32_bf16(a, w1h[s], acc1[rt], 0, 0, 0);
      acc0[rt] = __builtin_amdgcn_mfma_f32_16x16x32_bf16(b, w0h[s], acc0[rt], 0, 0, 0);
      acc1[rt] = __builtin_amdgcn_mfma_f32_16x16x32_bf16(b, w1h[s], acc1[rt], 0, 0, 0);
      acc0[rt] = __builtin_amdgcn_mfma_f32_16x16x32_bf16(a, w0l[s], acc0[rt], 0, 0, 0);
      acc1[rt] = __builtin_amdgcn_mfma_f32_16x16x32_bf16(a, w1l[s], acc1[rt], 0, 0, 0);
    }
  }

  int c0 = T0 * 16 + l15, c1 = T1 * 16 + l15;
  float av0 = (c0 < Uu) ? att_s[c0] : 0.f, dv0 = (c0 < Uu) ? att_d[c0] : 0.f;
  float av1 = (c1 < Uu) ? att_s[c1] : 0.f, dv1 = (c1 < Uu) ? att_d[c1] : 0.f;
#pragma unroll
  for (int rt = 0; rt < 4; ++rt) {
#pragma unroll
    for (int i = 0; i < 4; ++i) {
      float v0 = acc0[rt][i], v1 = acc1[rt][i];
      int row = rt * 16 + q * 4 + i;
      size_t m = (size_t)(m0 + row);
      if (c0 < Uu) h[m * Uu + c0] = v0;
      if (c1 < Uu) h[m * Uu + c1] = v1;
      float va = v0 * av0 + v1 * av1, vd = v0 * dv0 + v1 * dv1;
#pragma unroll
      for (int msk = 1; msk < 16; msk <<= 1) {
        va += __shfl_xor(va, msk, 64);
        vd += __shfl_xor(vd, msk, 64);
      }
      if (l15 == 0) {
        atomicAdd(&sredA[row], va);
        atomicAdd(&sredD[row], vd);
      }
    }
  }
  __syncthreads();
  if (tid < 64) {
    asrc[m0 + tid] = sredA[tid];
    adst[m0 + tid] = sredD[tid];
  }
}

// ---------------------------------------------------------------------------
// k_attn: one WAVE per (sample, dst). Unchanged from round 4 (passing).
// ---------------------------------------------------------------------------
__global__ __launch_bounds__(256) void k_attn(
    const int* __restrict__ coff, const int* __restrict__ cslot,
    const float* __restrict__ asrc, const float* __restrict__ adst,
    const float* __restrict__ h, const float* __restrict__ gbias, const float* __restrict__ b1,
    float* __restrict__ gsf) {
  int b = blockIdx.x;
  int w = threadIdx.x >> 6, lane = threadIdx.x & 63;
  int n = blockIdx.y * 4 + w;
  int o0 = coff[n], deg = coff[n + 1] - o0;
  float ad = adst[b * Nn + n];
  const float* hb = h + (size_t)b * Nn * Uu;
  int half = lane >> 5, ll = lane & 31;
  bool act = (ll < 25);

  float ax = 0.f, ay = 0.f, az = 0.f, aw = 0.f;
  float den = 0.f;
  for (int c0 = 0; c0 < deg; c0 += 64) {
    int e = c0 + lane;
    float we = 0.f; int s = 0;
    if (e < deg) {
      s = cslot[o0 + e];
      float sc = asrc[b * Nn + s] + ad;
      sc = (sc > 0.f) ? sc : 0.2f * sc;
      we = __expf(sc);
    }
    float d = we;
#pragma unroll
    for (int msk = 1; msk < 64; msk <<= 1) d += __shfl_xor(d, msk, 64);
    den += d;

    int cn = (deg - c0 < 64) ? (deg - c0) : 64;
    for (int e2 = 0; e2 < cn; e2 += 2) {
      int eh = e2 + half;
      float w2 = __shfl(we, eh, 64);
      int s2 = __shfl(s, eh, 64);
      if (act && eh < cn) {
        const float4 hv = *(const float4*)(hb + (size_t)s2 * Uu + ll * 4);
        ax += w2 * hv.x; ay += w2 * hv.y; az += w2 * hv.z; aw += w2 * hv.w;
      }
    }
  }
  ax += __shfl_xor(ax, 32, 64);
  ay += __shfl_xor(ay, 32, 64);
  az += __shfl_xor(az, 32, 64);
  aw += __shfl_xor(aw, 32, 64);
  if (lane < 25) {
    float inv = 1.f / den;
    int u0 = lane * 4;
    float4 o;
    o.x = ax * inv + gbias[u0 + 0] + b1[u0 + 0];
    o.y = ay * inv + gbias[u0 + 1] + b1[u0 + 1];
    o.z = az * inv + gbias[u0 + 2] + b1[u0 + 2];
    o.w = aw * inv + gbias[u0 + 3] + b1[u0 + 3];
    *(float4*)(gsf + ((size_t)b * Nn + n) * Uu + u0) = o;
  }
}

// ---------------------------------------------------------------------------
// k_gru (FUSED ru + c): A=[gstate|xi] split in LDS. Phase 1: ru GEMM (2
// weight-stationary passes over 16 tiles); r*st kept in regs, u-gate -> u16
// fixed-point LDS. Barrier; write split(r*st) over LDS gstate region;
// barrier; phase 2: c GEMM + tanh + blend. No cat2/ugf global buffers.
// ---------------------------------------------------------------------------
__global__ __launch_bounds__(256, 3) void k_gru(
    const float* __restrict__ gsf, const float* __restrict__ inp,
    const u16* __restrict__ wruh, const u16* __restrict__ wrul,
    const float* __restrict__ bru,
    const u16* __restrict__ wch, const u16* __restrict__ wcl,
    const float* __restrict__ bc,
    float* __restrict__ out) {
  __shared__ u16 ahL[64 * AS];
  __shared__ u16 alL[64 * AS];
  __shared__ u16 ugQ[64 * Uu];     // u-gate, 16-bit fixed point
  int tid = threadIdx.x;
  int m0 = blockIdx.x * 64;
  for (int j = tid; j < 64 * 32; j += 256) {
    int r = j >> 5, g = j & 31;
    float4 v = (g < 25) ? *(const float4*)(gsf + (size_t)(m0 + r) * Uu + g * 4)
                        : *(const float4*)(inp + (size_t)(m0 + r) * Ff + (g - 25) * 4);
    ushort4 hh, ll;
    split4(v, hh, ll);
    *(ushort4*)(ahL + r * AS + g * 4) = hh;
    *(ushort4*)(alL + r * AS + g * 4) = ll;
  }
  __syncthreads();

  int w = tid >> 6, l = tid & 63, l15 = l & 15, q = l >> 4;
  f32x4 zero = {0.f, 0.f, 0.f, 0.f};
  float pr[2][4][4];               // r*st (pass-0 tiles, c<100 only)

  // ---- phase 1: ru ----
#pragma unroll
  for (int pass = 0; pass < 2; ++pass) {
    int T0 = pass * 8 + w, T1 = T0 + 4;
    bf16x8 w0h[4], w0l[4], w1h[4], w1l[4];
#pragma unroll
    for (int s = 0; s < 4; ++s) {
      const int o0 = (T0 * 16 + l15) * Kk + s * 32 + q * 8;
      const int o1 = (T1 * 16 + l15) * Kk + s * 32 + q * 8;
      w0h[s] = *(const bf16x8*)(wruh + o0);
      w0l[s] = *(const bf16x8*)(wrul + o0);
      w1h[s] = *(const bf16x8*)(wruh + o1);
      w1l[s] = *(const bf16x8*)(wrul + o1);
    }
    f32x4 acc0[4], acc1[4];
#pragma unroll
    for (int rt = 0; rt < 4; ++rt) { acc0[rt] = zero; acc1[rt] = zero; }
#pragma unroll
    for (int rt = 0; rt < 4; ++rt) {
#pragma unroll
      for (int s = 0; s < 4; ++s) {
        bf16x8 a = *(const bf16x8*)(ahL + (rt * 16 + l15) * AS + s * 32 + q * 8);
        bf16x8 b = *(const bf16x8*)(alL + (rt * 16 + l15) * AS + s * 32 + q * 8);
        acc0[rt] = __builtin_amdgcn_mfma_f32_16x16x32_bf16(a, w0h[s], acc0[rt], 0, 0, 0);
        acc1[rt] = __builtin_amdgcn_mfma_f32_16x16x32_bf16(a, w1h[s], acc1[rt], 0, 0, 0);
        acc0[rt] = __builtin_amdgcn_mfma_f32_16x16x32_bf16(b, w0h[s], acc0[rt], 0, 0, 0);
        acc1[rt] = __builtin_amdgcn_mfma_f32_16x16x32_bf16(b, w1h[s], acc1[rt], 0, 0, 0);
        acc0[rt] = __builtin_amdgcn_mfma_f32_16x16x32_bf16(a, w0l[s], acc0[rt], 0, 0, 0);
        acc1[rt] = __builtin_amdgcn_mfma_f32_16x16x32_bf16(a, w1l[s], acc1[rt], 0, 0, 0);
      }
    }
    int c0 = T0 * 16 + l15, c1 = T1 * 16 + l15;
    float bv0 = (c0 < 2 * Uu) ? bru[c0] : 0.f;
    float bv1 = (c1 < 2 * Uu) ? bru[c1] : 0.f;
#pragma unroll
    for (int rt = 0; rt < 4; ++rt) {
#pragma unroll
      for (int i = 0; i < 4; ++i) {
        int row = rt * 16 + q * 4 + i;
#pragma unroll
        for (int t = 0; t < 2; ++t) {
          int c = t ? c1 : c0;
          float y = (t ? acc1[rt][i] : acc0[rt][i]) + (t ? bv1 : bv0);
          float g = 1.f / (1.f + __expf(-y));
          if (c < Uu) {
            // r gate: p = g * st (st reconstructed from split LDS, read-only)
            float st = bf2f(ahL[row * AS + c]) + bf2f(alL[row * AS + c]);
            pr[t][rt][i] = g * st;
          } else if (c < 2 * Uu) {
            ugQ[row * Uu + (c - Uu)] = (u16)(g * 65535.f + 0.5f);
          }
        }
      }
    }
  }

  __syncthreads();   // all phase-1 LDS reads complete
  {
    int c0p = w * 16 + l15, c1p = (w + 4) * 16 + l15;
#pragma unroll
    for (int rt = 0; rt < 4; ++rt) {
#pragma unroll
      for (int i = 0; i < 4; ++i) {
        int row = rt * 16 + q * 4 + i;
#pragma unroll
        for (int t = 0; t < 2; ++t) {
          int c = t ? c1p : c0p;
          if (c < Uu) {
            float p = pr[t][rt][i];
            u16 hh = f2bf(p);
            ahL[row * AS + c] = hh;
            alL[row * AS + c] = f2bf(p - bf2f(hh));
          }
        }
      }
    }
  }
  __syncthreads();   // cat2 = [r*st | xi] (split) ready in LDS

  // ---- phase 2: c GEMM + blend ----
  {
    int T0 = w, T1 = w + 4;
    bf16x8 w0h[4], w0l[4], w1h[4], w1l[4];
#pragma unroll
    for (int s = 0; s < 4; ++s) {
      const int o0 = (T0 * 16 + l15) * Kk + s * 32 + q * 8;
      const int o1 = (T1 * 16 + l15) * Kk + s * 32 + q * 8;
      w0h[s] = *(const bf16x8*)(wch + o0);
      w0l[s] = *(const bf16x8*)(wcl + o0);
      w1h[s] = *(const bf16x8*)(wch + o1);
      w1l[s] = *(const bf16x8*)(wcl + o1);
    }
    f32x4 acc0[4], acc1[4];
#pragma unroll
    for (int rt = 0; rt < 4; ++rt) { acc0[rt] = zero; acc1[rt] = zero; }
#pragma unroll
    for (int rt = 0; rt < 4; ++rt) {
#pragma unroll
      for (int s = 0; s < 4; ++s) {
        bf16x8 a = *(const bf16x8*)(ahL + (rt * 16 + l15) * AS + s * 32 + q * 8);
        bf16x8 b = *(const bf16x8*)(alL + (rt * 16 + l15) * AS + s * 32 + q * 8);
        acc0[rt] = __builtin_amdgcn_mfma_f32_16x16x32_bf16(a, w0h[s], acc0[rt], 0, 0, 0);
        acc1[rt] = __builtin_amdgcn_mfma_f32_16x16x32_bf16(a, w1h[s], acc1[rt], 0, 0, 0);
        acc0[rt] = __builtin_amdgcn_mfma_f32_16x16x32_bf16(b, w0h[s], acc0[rt], 0, 0, 0);
        acc1[rt] = __builtin_amdgcn_mfma_f32_16x16x32_bf16(b, w1h[s], acc1[rt], 0, 0, 0);
        acc0[rt] = __builtin_amdgcn_mfma_f32_16x16x32_bf16(a, w0l[s], acc0[rt], 0, 0, 0);
        acc1[rt] = __builtin_amdgcn_mfma_f32_16x16x32_bf16(a, w1l[s], acc1[rt], 0, 0, 0);
      }
    }
    int c0 = T0 * 16 + l15, c1 = T1 * 16 + l15;
    float bv0 = (c0 < Uu) ? bc[c0] : 0.f;
    float bv1 = (c1 < Uu) ? bc[c1] : 0.f;
#pragma unroll
    for (int rt = 0; rt < 4; ++rt) {
#pragma unroll
      for (int i = 0; i < 4; ++i) {
        int row = rt * 16 + q * 4 + i;
        size_t m = (size_t)(m0 + row);
#pragma unroll
        for (int t = 0; t < 2; ++t) {
          int c = t ? c1 : c0;
          if (c < Uu) {
            float y = (t ? acc1[rt][i] : acc0[rt][i]) + (t ? bv1 : bv0);
            float cv = 1.f - 2.f / (__expf(2.f * y) + 1.f);
            float u = (float)ugQ[row * Uu + c] * (1.f / 65535.f);
            float sv = gsf[m * Uu + c];
            out[m * Uu + c] = u * sv + (1.f - u) * cv;
          }
        }
      }
    }
  }
}

// ---------------------------------------------------------------------------
extern "C" void kernel_launch(void* const* d_in, const int* in_sizes, int n_in,
                              void* d_out, int out_size, void* d_ws, size_t ws_size,
                              hipStream_t stream) {
  const float* inp   = (const float*)d_in[0];
  const float* stt   = (const float*)d_in[1];
  const int*   esrc  = (const int*)d_in[2];
  const int*   edst  = (const int*)d_in[3];
  const float* Wg    = (const float*)d_in[4];
  const float* att_s = (const float*)d_in[5];
  const float* att_d = (const float*)d_in[6];
  const float* gbias = (const float*)d_in[7];
  const float* b1    = (const float*)d_in[8];
  const float* Wru   = (const float*)d_in[9];
  const float* bru   = (const float*)d_in[10];
  const float* Wc    = (const float*)d_in[11];
  const float* bc    = (const float*)d_in[12];
  float* out = (float*)d_out;

  char* base = (char*)d_ws;
  size_t o = 0;
  auto alloc = [&](size_t bytes) -> void* {
    void* p = base + o;
    o = (o + bytes + 255) & ~(size_t)255;
    return p;
  };
  u16* wgh  = (u16*)alloc(128 * Kk * sizeof(u16));
  u16* wgl  = (u16*)alloc(128 * Kk * sizeof(u16));
  u16* wruh = (u16*)alloc(256 * Kk * sizeof(u16));
  u16* wrul = (u16*)alloc(256 * Kk * sizeof(u16));
  u16* wch  = (u16*)alloc(128 * Kk * sizeof(u16));
  u16* wcl  = (u16*)alloc(128 * Kk * sizeof(u16));
  int* coff  = (int*)alloc((Nn + 1) * sizeof(int));
  int* cslot = (int*)alloc(ET * sizeof(int));
  float* h    = (float*)alloc((size_t)Mrows * Uu * sizeof(float));
  float* asrc = (float*)alloc((size_t)Mrows * sizeof(float));
  float* adst = (float*)alloc((size_t)Mrows * sizeof(float));
  float* gsf  = (float*)alloc((size_t)Mrows * Uu * sizeof(float));
  // total ~47.6 MB — at/below the round-4 footprint that passed

  k_prep<<<32, 256, 0, stream>>>(Wg, Wru, Wc, wgh, wgl, wruh, wrul, wch, wcl);
  k_csr<<<1, 256, 0, stream>>>(esrc, edst, coff, cslot);
  k_gemm1<<<Mrows / 64, 256, 0, stream>>>(stt, inp, wgh, wgl, att_s, att_d, h, asrc, adst);
  k_attn<<<dim3(Bb, 60), 256, 0, stream>>>(coff, cslot, asrc, adst, h, gbias, b1, gsf);
  k_gru<<<Mrows / 64, 256, 0, stream>>>(gsf, inp, wruh, wrul, bru, wch, wcl, bc, out);
}